// Round 1
// baseline (253.103 us; speedup 1.0000x reference)
//
#include <hip/hip_runtime.h>

// Problem constants (from reference setup_inputs)
#define N_PRE_C   50000
#define N_TYPES_C 20
#define N_BASIS_C 5
#define NB        2                    // batches
#define WORDS     784                  // ceil(50000/64)=782, padded to 784 (784*64 = 50176)

// ---------------------------------------------------------------------------
// Kernel 1: pack rec_z_buf (B x N_PRE floats, binary) into a bitmask.
// Layout in ws: mask[word][b]  (interleaved so main kernel reads both batches
// with one ds_read_b128 after staging in LDS).
// ---------------------------------------------------------------------------
__global__ __launch_bounds__(256) void pack_spikes(const float* __restrict__ rec_z,
                                                   unsigned long long* __restrict__ mask) {
    const int b = blockIdx.y;
    const int i = blockIdx.x * 256 + threadIdx.x;   // [0, WORDS*64)
    float v = 0.f;
    if (i < N_PRE_C) v = rec_z[b * N_PRE_C + i];
    unsigned long long m = __ballot(v > 0.f);       // 64-bit wave mask
    if ((threadIdx.x & 63) == 0) mask[(i >> 6) * NB + b] = m;
}

// ---------------------------------------------------------------------------
// Kernel 2: stream synapses, gate by spike bit, scatter-add into out.
// ---------------------------------------------------------------------------
__device__ __forceinline__ void do_syn(int post, int pre, float w, int sid,
                                       const unsigned long long (*sm)[2],
                                       const float (*sb)[N_BASIS_C],
                                       float* __restrict__ out, int n_post) {
    const int word = pre >> 6;
    const unsigned long long m0 = sm[word][0];
    const unsigned long long m1 = sm[word][1];
    const unsigned long long bit = 1ull << (pre & 63);
    if (((m0 | m1) & bit) == 0ull) return;          // ~96% early-out

    const float* bs = sb[sid];
    const float c0 = w * bs[0];
    const float c1 = w * bs[1];
    const float c2 = w * bs[2];
    const float c3 = w * bs[3];
    const float c4 = w * bs[4];

    if (m0 & bit) {
        float* o = out + (long)post * N_BASIS_C;
        atomicAdd(o + 0, c0); atomicAdd(o + 1, c1); atomicAdd(o + 2, c2);
        atomicAdd(o + 3, c3); atomicAdd(o + 4, c4);
    }
    if (m1 & bit) {
        float* o = out + ((long)n_post + post) * N_BASIS_C;
        atomicAdd(o + 0, c0); atomicAdd(o + 1, c1); atomicAdd(o + 2, c2);
        atomicAdd(o + 3, c3); atomicAdd(o + 4, c4);
    }
}

__global__ __launch_bounds__(256) void syn_scatter(
    const int4*  __restrict__ idx2,    // synapse_indices as int4 = 2 synapses (post,pre,post,pre)
    const float4* __restrict__ w4,     // weights, 4 per thread
    const int4*  __restrict__ sid4,    // syn_ids, 4 per thread
    const float* __restrict__ basis,   // [N_TYPES][N_BASIS]
    const unsigned long long* __restrict__ mask,  // [WORDS][2]
    const int*   __restrict__ n_post_p,
    float* __restrict__ out,           // [B][n_post][N_BASIS]
    int n_syn) {
    __shared__ __align__(16) unsigned long long sm[WORDS][2];
    __shared__ float sb[N_TYPES_C][N_BASIS_C];

    for (int t = threadIdx.x; t < WORDS * 2; t += 256)
        ((unsigned long long*)sm)[t] = mask[t];
    for (int t = threadIdx.x; t < N_TYPES_C * N_BASIS_C; t += 256)
        ((float*)sb)[t] = basis[t];
    __syncthreads();

    const int n_post = *n_post_p;
    const long tid  = (long)blockIdx.x * 256 + threadIdx.x;
    const long base = tid * 4;
    if (base >= n_syn) return;

    if (base + 4 <= n_syn) {
        // Fully coalesced vector loads: 32B idx + 16B w + 16B sid per lane.
        const int4  p01 = idx2[tid * 2];
        const int4  p23 = idx2[tid * 2 + 1];
        const float4 wv = w4[tid];
        const int4   sv = sid4[tid];
        do_syn(p01.x, p01.y, wv.x, sv.x, sm, sb, out, n_post);
        do_syn(p01.z, p01.w, wv.y, sv.y, sm, sb, out, n_post);
        do_syn(p23.x, p23.y, wv.z, sv.z, sm, sb, out, n_post);
        do_syn(p23.z, p23.w, wv.w, sv.w, sm, sb, out, n_post);
    } else {
        // Scalar tail (not hit for N_SYN = 10M, kept for generality).
        const int*   idx = (const int*)idx2;
        const float* w   = (const float*)w4;
        const int*   sid = (const int*)sid4;
        for (long s = base; s < n_syn; ++s)
            do_syn(idx[2 * s], idx[2 * s + 1], w[s], sid[s], sm, sb, out, n_post);
    }
}

extern "C" void kernel_launch(void* const* d_in, const int* in_sizes, int n_in,
                              void* d_out, int out_size, void* d_ws, size_t ws_size,
                              hipStream_t stream) {
    const float* rec_z   = (const float*)d_in[0];        // [B, N_PRE]
    const float* weights = (const float*)d_in[1];        // [N_SYN]
    const float* basis   = (const float*)d_in[2];        // [N_TYPES, N_BASIS]
    const int*   synidx  = (const int*)d_in[3];          // [N_SYN, 2]
    const int*   synids  = (const int*)d_in[4];          // [N_SYN]
    const int*   n_post  = (const int*)d_in[5];          // scalar
    float*       out     = (float*)d_out;

    const int n_syn = in_sizes[4];

    // Workspace: spike bitmask, WORDS*2 uint64 = 12544 bytes.
    unsigned long long* mask = (unsigned long long*)d_ws;

    // Output is poisoned before every timed launch — zero it (2 MB).
    hipMemsetAsync(d_out, 0, (size_t)out_size * sizeof(float), stream);

    // Pack spikes into bitmask.
    pack_spikes<<<dim3(WORDS * 64 / 256, NB), 256, 0, stream>>>(rec_z, mask);

    // Scatter synapses: 4 synapses/thread.
    const long n_thr = ((long)n_syn + 3) / 4;
    const int  blocks = (int)((n_thr + 255) / 256);
    syn_scatter<<<blocks, 256, 0, stream>>>(
        (const int4*)synidx, (const float4*)weights, (const int4*)synids,
        basis, mask, n_post, out, n_syn);
}

// Round 2
// 201.984 us; speedup vs baseline: 1.2531x; 1.2531x over previous
//
#include <hip/hip_runtime.h>

// Problem constants (from reference setup_inputs)
#define N_PRE_C   50000
#define N_TYPES_C 20
#define N_BASIS_C 5
#define NB        2                    // batches
#define WORDS     784                  // ceil(50000/64)=782, padded to 784

typedef unsigned long long ull;

// ---------------------------------------------------------------------------
// Kernel 1: pack rec_z_buf (B x N_PRE floats, binary) into a bitmask.
// Layout: mask[word][b] interleaved.
// ---------------------------------------------------------------------------
__global__ __launch_bounds__(256) void pack_spikes(const float* __restrict__ rec_z,
                                                   ull* __restrict__ mask) {
    const int b = blockIdx.y;
    const int i = blockIdx.x * 256 + threadIdx.x;   // [0, WORDS*64)
    float v = 0.f;
    if (i < N_PRE_C) v = rec_z[b * N_PRE_C + i];
    ull m = __ballot(v > 0.f);
    if ((threadIdx.x & 63) == 0) mask[(i >> 6) * NB + b] = m;
}

// ---------------------------------------------------------------------------
// Kernel 2a (main path): scatter into per-(b,post,TYPE) accumulator.
// One atomic per spike-hit instead of five. w/sid loads deferred to hit path.
// ---------------------------------------------------------------------------
__device__ __forceinline__ void proc_t(int post, int pre, int s,
                                       const ull (*sm)[2],
                                       const float* __restrict__ w,
                                       const int* __restrict__ sid,
                                       float* __restrict__ out_t, int n_post) {
    const int word = pre >> 6;
    const ull m0 = sm[word][0];
    const ull m1 = sm[word][1];
    const ull bit = 1ull << (pre & 63);
    if (((m0 | m1) & bit) == 0ull) return;          // ~96% early-out
    const float wv = w[s];
    const int   tt = sid[s];
    if (m0 & bit) atomicAdd(out_t + (long)post * N_TYPES_C + tt, wv);
    if (m1 & bit) atomicAdd(out_t + (long)(n_post + post) * N_TYPES_C + tt, wv);
}

__global__ __launch_bounds__(256) void syn_scatter_t(
    const int4* __restrict__ idx2,     // 2 synapses per int4 (post,pre,post,pre)
    const float* __restrict__ w,
    const int*  __restrict__ sid,
    const ull*  __restrict__ mask,
    float* __restrict__ out_t,         // [NB*n_post][N_TYPES] accumulator (zeroed)
    int n_post, int n_syn, int n_thr) {
    __shared__ __align__(16) ull sm[WORDS][2];
    for (int t = threadIdx.x; t < WORDS * 2; t += 256)
        ((ull*)sm)[t] = mask[t];
    __syncthreads();

    const int stride = gridDim.x * 256;
    for (int t = blockIdx.x * 256 + threadIdx.x; t < n_thr; t += stride) {
        const int base = t << 2;
        if (base + 4 <= n_syn) {
            const int4 p01 = idx2[(long)t * 2];
            const int4 p23 = idx2[(long)t * 2 + 1];
            proc_t(p01.x, p01.y, base + 0, sm, w, sid, out_t, n_post);
            proc_t(p01.z, p01.w, base + 1, sm, w, sid, out_t, n_post);
            proc_t(p23.x, p23.y, base + 2, sm, w, sid, out_t, n_post);
            proc_t(p23.z, p23.w, base + 3, sm, w, sid, out_t, n_post);
        } else {
            const int* idx = (const int*)idx2;
            for (int s = base; s < n_syn; ++s)
                proc_t(idx[2 * s], idx[2 * s + 1], s, sm, w, sid, out_t, n_post);
        }
    }
}

// ---------------------------------------------------------------------------
// Kernel 3: combine out_t [rows][20] x basis [20][5] -> out [rows][5].
// ---------------------------------------------------------------------------
__global__ __launch_bounds__(256) void combine_basis(
    const float* __restrict__ out_t,
    const float* __restrict__ basis,   // [N_TYPES][N_BASIS]
    float* __restrict__ out, int rows) {
    __shared__ float sb[N_TYPES_C * N_BASIS_C];
    if (threadIdx.x < N_TYPES_C * N_BASIS_C) sb[threadIdx.x] = basis[threadIdx.x];
    __syncthreads();

    const int r = blockIdx.x * 256 + threadIdx.x;
    if (r >= rows) return;
    const float4* p = (const float4*)(out_t + (long)r * N_TYPES_C);
    float4 v0 = p[0], v1 = p[1], v2 = p[2], v3 = p[3], v4 = p[4];
    float vt[N_TYPES_C] = {v0.x, v0.y, v0.z, v0.w, v1.x, v1.y, v1.z, v1.w,
                           v2.x, v2.y, v2.z, v2.w, v3.x, v3.y, v3.z, v3.w,
                           v4.x, v4.y, v4.z, v4.w};
    float acc[N_BASIS_C] = {0.f, 0.f, 0.f, 0.f, 0.f};
    #pragma unroll
    for (int t = 0; t < N_TYPES_C; ++t) {
        #pragma unroll
        for (int k = 0; k < N_BASIS_C; ++k)
            acc[k] += vt[t] * sb[t * N_BASIS_C + k];   // sb read is a broadcast
    }
    float* o = out + (long)r * N_BASIS_C;
    #pragma unroll
    for (int k = 0; k < N_BASIS_C; ++k) o[k] = acc[k];
}

// ---------------------------------------------------------------------------
// Fallback (only if ws too small): direct 5-atomic scatter into out.
// ---------------------------------------------------------------------------
__device__ __forceinline__ void proc_direct(int post, int pre, int s,
                                            const ull (*sm)[2],
                                            const float* __restrict__ w,
                                            const int* __restrict__ sid,
                                            const float (*sb)[N_BASIS_C],
                                            float* __restrict__ out, int n_post) {
    const int word = pre >> 6;
    const ull m0 = sm[word][0], m1 = sm[word][1];
    const ull bit = 1ull << (pre & 63);
    if (((m0 | m1) & bit) == 0ull) return;
    const float wv = w[s];
    const float* bs = sb[sid[s]];
    float c[N_BASIS_C];
    #pragma unroll
    for (int k = 0; k < N_BASIS_C; ++k) c[k] = wv * bs[k];
    if (m0 & bit) {
        float* o = out + (long)post * N_BASIS_C;
        #pragma unroll
        for (int k = 0; k < N_BASIS_C; ++k) atomicAdd(o + k, c[k]);
    }
    if (m1 & bit) {
        float* o = out + (long)(n_post + post) * N_BASIS_C;
        #pragma unroll
        for (int k = 0; k < N_BASIS_C; ++k) atomicAdd(o + k, c[k]);
    }
}

__global__ __launch_bounds__(256) void syn_scatter_direct(
    const int4* __restrict__ idx2, const float* __restrict__ w,
    const int* __restrict__ sid, const float* __restrict__ basis,
    const ull* __restrict__ mask, float* __restrict__ out,
    int n_post, int n_syn, int n_thr) {
    __shared__ __align__(16) ull sm[WORDS][2];
    __shared__ float sb[N_TYPES_C][N_BASIS_C];
    for (int t = threadIdx.x; t < WORDS * 2; t += 256) ((ull*)sm)[t] = mask[t];
    for (int t = threadIdx.x; t < N_TYPES_C * N_BASIS_C; t += 256)
        ((float*)sb)[t] = basis[t];
    __syncthreads();
    const int stride = gridDim.x * 256;
    for (int t = blockIdx.x * 256 + threadIdx.x; t < n_thr; t += stride) {
        const int base = t << 2;
        if (base + 4 <= n_syn) {
            const int4 p01 = idx2[(long)t * 2];
            const int4 p23 = idx2[(long)t * 2 + 1];
            proc_direct(p01.x, p01.y, base + 0, sm, w, sid, sb, out, n_post);
            proc_direct(p01.z, p01.w, base + 1, sm, w, sid, sb, out, n_post);
            proc_direct(p23.x, p23.y, base + 2, sm, w, sid, sb, out, n_post);
            proc_direct(p23.z, p23.w, base + 3, sm, w, sid, sb, out, n_post);
        } else {
            const int* idx = (const int*)idx2;
            for (int s = base; s < n_syn; ++s)
                proc_direct(idx[2 * s], idx[2 * s + 1], s, sm, w, sid, sb, out, n_post);
        }
    }
}

extern "C" void kernel_launch(void* const* d_in, const int* in_sizes, int n_in,
                              void* d_out, int out_size, void* d_ws, size_t ws_size,
                              hipStream_t stream) {
    const float* rec_z   = (const float*)d_in[0];
    const float* weights = (const float*)d_in[1];
    const float* basis   = (const float*)d_in[2];
    const int*   synidx  = (const int*)d_in[3];
    const int*   synids  = (const int*)d_in[4];
    float*       out     = (float*)d_out;

    const int n_syn  = in_sizes[4];
    const int rows   = out_size / N_BASIS_C;       // NB * n_post
    const int n_post = rows / NB;
    const int n_thr  = (n_syn + 3) / 4;

    // Workspace layout: out_t [rows][N_TYPES] floats, then mask.
    const size_t out_t_bytes = (size_t)rows * N_TYPES_C * sizeof(float);
    const size_t mask_bytes  = (size_t)WORDS * NB * sizeof(ull);

    const int scatter_blocks = 2048;               // grid-stride; 8 blocks/CU

    if (ws_size >= out_t_bytes + mask_bytes) {
        float* out_t = (float*)d_ws;
        ull*   mask  = (ull*)((char*)d_ws + out_t_bytes);

        hipMemsetAsync(out_t, 0, out_t_bytes, stream);
        pack_spikes<<<dim3(WORDS * 64 / 256, NB), 256, 0, stream>>>(rec_z, mask);
        syn_scatter_t<<<scatter_blocks, 256, 0, stream>>>(
            (const int4*)synidx, weights, synids, mask, out_t,
            n_post, n_syn, n_thr);
        combine_basis<<<(rows + 255) / 256, 256, 0, stream>>>(out_t, basis, out, rows);
    } else {
        // Fallback: direct 5-atomic scatter (R1 behavior).
        ull* mask = (ull*)d_ws;
        hipMemsetAsync(d_out, 0, (size_t)out_size * sizeof(float), stream);
        pack_spikes<<<dim3(WORDS * 64 / 256, NB), 256, 0, stream>>>(rec_z, mask);
        syn_scatter_direct<<<scatter_blocks, 256, 0, stream>>>(
            (const int4*)synidx, weights, synids, basis, mask, out,
            n_post, n_syn, n_thr);
    }
}

// Round 3
// 194.892 us; speedup vs baseline: 1.2987x; 1.0364x over previous
//
#include <hip/hip_runtime.h>

// Problem constants (from reference setup_inputs)
#define N_PRE_C   50000
#define N_TYPES_C 20
#define N_BASIS_C 5
#define NB        2                    // batches
#define WORDS     784                  // ceil(50000/64)=782, padded to 784

typedef unsigned long long ull;

// ---------------------------------------------------------------------------
// Kernel 1: pack rec_z_buf (B x N_PRE floats, binary) into a bitmask.
// Layout: mask[word][b] interleaved so one 16B LDS read covers both batches.
// ---------------------------------------------------------------------------
__global__ __launch_bounds__(256) void pack_spikes(const float* __restrict__ rec_z,
                                                   ull* __restrict__ mask) {
    const int b = blockIdx.y;
    const int i = blockIdx.x * 256 + threadIdx.x;   // [0, WORDS*64)
    float v = 0.f;
    if (i < N_PRE_C) v = rec_z[b * N_PRE_C + i];
    ull m = __ballot(v > 0.f);
    if ((threadIdx.x & 63) == 0) mask[(i >> 6) * NB + b] = m;
}

// ---------------------------------------------------------------------------
// Kernel 2: scatter into per-(b,post,TYPE) accumulator.
// One-shot threads (no grid-stride), unconditional coalesced loads, and
// unsafeAtomicAdd (HW global_atomic_add_f32, no return -> fire-and-forget:
// the wave never waits on atomic completion; no CAS loop).
// ---------------------------------------------------------------------------
__device__ __forceinline__ void proc_t(int post, int pre, float wv, int tt,
                                       const ull (*sm)[2],
                                       float* __restrict__ out_t, int n_post) {
    const int word = pre >> 6;
    const ull m0 = sm[word][0];
    const ull m1 = sm[word][1];
    const ull bit = 1ull << (pre & 63);
    if (((m0 | m1) & bit) == 0ull) return;          // ~96% early-out
    if (m0 & bit) unsafeAtomicAdd(out_t + (long)post * N_TYPES_C + tt, wv);
    if (m1 & bit) unsafeAtomicAdd(out_t + (long)(n_post + post) * N_TYPES_C + tt, wv);
}

__global__ __launch_bounds__(256) void syn_scatter_t(
    const int4*  __restrict__ idx2,    // 2 synapses per int4 (post,pre,post,pre)
    const float4* __restrict__ w4,
    const int4*  __restrict__ sid4,
    const ull*   __restrict__ mask,
    float* __restrict__ out_t,         // [NB*n_post][N_TYPES] accumulator (zeroed)
    int n_post, int n_syn) {
    __shared__ __align__(16) ull sm[WORDS][2];
    {   // stage mask with 16B loads
        const ulonglong2* msrc = (const ulonglong2*)mask;
        ulonglong2* mdst = (ulonglong2*)sm;
        for (int t = threadIdx.x; t < WORDS; t += 256) mdst[t] = msrc[t];
    }
    __syncthreads();

    const int t = blockIdx.x * 256 + threadIdx.x;
    const long base = (long)t * 4;
    if (base >= n_syn) return;

    if (base + 4 <= n_syn) {
        // Coalesced vector loads issued before any atomic: 32B idx + 16B w + 16B sid.
        const int4   p01 = idx2[(long)t * 2];
        const int4   p23 = idx2[(long)t * 2 + 1];
        const float4 wv  = w4[t];
        const int4   sv  = sid4[t];
        proc_t(p01.x, p01.y, wv.x, sv.x, sm, out_t, n_post);
        proc_t(p01.z, p01.w, wv.y, sv.y, sm, out_t, n_post);
        proc_t(p23.x, p23.y, wv.z, sv.z, sm, out_t, n_post);
        proc_t(p23.z, p23.w, wv.w, sv.w, sm, out_t, n_post);
    } else {
        const int*   idx = (const int*)idx2;
        const float* w   = (const float*)w4;
        const int*   sid = (const int*)sid4;
        for (long s = base; s < n_syn; ++s)
            proc_t(idx[2 * s], idx[2 * s + 1], w[s], sid[s], sm, out_t, n_post);
    }
}

// ---------------------------------------------------------------------------
// Kernel 3: combine out_t [rows][20] x basis [20][5] -> out [rows][5].
// ---------------------------------------------------------------------------
__global__ __launch_bounds__(256) void combine_basis(
    const float* __restrict__ out_t,
    const float* __restrict__ basis,   // [N_TYPES][N_BASIS]
    float* __restrict__ out, int rows) {
    __shared__ float sb[N_TYPES_C * N_BASIS_C];
    if (threadIdx.x < N_TYPES_C * N_BASIS_C) sb[threadIdx.x] = basis[threadIdx.x];
    __syncthreads();

    const int r = blockIdx.x * 256 + threadIdx.x;
    if (r >= rows) return;
    const float4* p = (const float4*)(out_t + (long)r * N_TYPES_C);
    float4 v0 = p[0], v1 = p[1], v2 = p[2], v3 = p[3], v4 = p[4];
    float vt[N_TYPES_C] = {v0.x, v0.y, v0.z, v0.w, v1.x, v1.y, v1.z, v1.w,
                           v2.x, v2.y, v2.z, v2.w, v3.x, v3.y, v3.z, v3.w,
                           v4.x, v4.y, v4.z, v4.w};
    float acc[N_BASIS_C] = {0.f, 0.f, 0.f, 0.f, 0.f};
    #pragma unroll
    for (int t = 0; t < N_TYPES_C; ++t) {
        #pragma unroll
        for (int k = 0; k < N_BASIS_C; ++k)
            acc[k] += vt[t] * sb[t * N_BASIS_C + k];   // sb read is a broadcast
    }
    float* o = out + (long)r * N_BASIS_C;
    #pragma unroll
    for (int k = 0; k < N_BASIS_C; ++k) o[k] = acc[k];
}

// ---------------------------------------------------------------------------
// Fallback (only if ws too small): direct 5-atomic scatter into out.
// ---------------------------------------------------------------------------
__device__ __forceinline__ void proc_direct(int post, int pre, float wv, int tt,
                                            const ull (*sm)[2],
                                            const float (*sb)[N_BASIS_C],
                                            float* __restrict__ out, int n_post) {
    const int word = pre >> 6;
    const ull m0 = sm[word][0], m1 = sm[word][1];
    const ull bit = 1ull << (pre & 63);
    if (((m0 | m1) & bit) == 0ull) return;
    const float* bs = sb[tt];
    float c[N_BASIS_C];
    #pragma unroll
    for (int k = 0; k < N_BASIS_C; ++k) c[k] = wv * bs[k];
    if (m0 & bit) {
        float* o = out + (long)post * N_BASIS_C;
        #pragma unroll
        for (int k = 0; k < N_BASIS_C; ++k) unsafeAtomicAdd(o + k, c[k]);
    }
    if (m1 & bit) {
        float* o = out + (long)(n_post + post) * N_BASIS_C;
        #pragma unroll
        for (int k = 0; k < N_BASIS_C; ++k) unsafeAtomicAdd(o + k, c[k]);
    }
}

__global__ __launch_bounds__(256) void syn_scatter_direct(
    const int4* __restrict__ idx2, const float4* __restrict__ w4,
    const int4* __restrict__ sid4, const float* __restrict__ basis,
    const ull* __restrict__ mask, float* __restrict__ out,
    int n_post, int n_syn) {
    __shared__ __align__(16) ull sm[WORDS][2];
    __shared__ float sb[N_TYPES_C][N_BASIS_C];
    for (int t = threadIdx.x; t < WORDS * 2; t += 256) ((ull*)sm)[t] = mask[t];
    for (int t = threadIdx.x; t < N_TYPES_C * N_BASIS_C; t += 256)
        ((float*)sb)[t] = basis[t];
    __syncthreads();
    const int t = blockIdx.x * 256 + threadIdx.x;
    const long base = (long)t * 4;
    if (base >= n_syn) return;
    if (base + 4 <= n_syn) {
        const int4   p01 = idx2[(long)t * 2];
        const int4   p23 = idx2[(long)t * 2 + 1];
        const float4 wv  = w4[t];
        const int4   sv  = sid4[t];
        proc_direct(p01.x, p01.y, wv.x, sv.x, sm, sb, out, n_post);
        proc_direct(p01.z, p01.w, wv.y, sv.y, sm, sb, out, n_post);
        proc_direct(p23.x, p23.y, wv.z, sv.z, sm, sb, out, n_post);
        proc_direct(p23.z, p23.w, wv.w, sv.w, sm, sb, out, n_post);
    } else {
        const int*   idx = (const int*)idx2;
        const float* w   = (const float*)w4;
        const int*   sid = (const int*)sid4;
        for (long s = base; s < n_syn; ++s)
            proc_direct(idx[2 * s], idx[2 * s + 1], w[s], sid[s], sm, sb, out, n_post);
    }
}

extern "C" void kernel_launch(void* const* d_in, const int* in_sizes, int n_in,
                              void* d_out, int out_size, void* d_ws, size_t ws_size,
                              hipStream_t stream) {
    const float* rec_z   = (const float*)d_in[0];
    const float* weights = (const float*)d_in[1];
    const float* basis   = (const float*)d_in[2];
    const int*   synidx  = (const int*)d_in[3];
    const int*   synids  = (const int*)d_in[4];
    float*       out     = (float*)d_out;

    const int n_syn  = in_sizes[4];
    const int rows   = out_size / N_BASIS_C;       // NB * n_post
    const int n_post = rows / NB;
    const int n_thr  = (n_syn + 3) / 4;
    const int blocks = (n_thr + 255) / 256;        // one-shot mapping

    // Workspace layout: out_t [rows][N_TYPES] floats, then mask.
    const size_t out_t_bytes = (size_t)rows * N_TYPES_C * sizeof(float);
    const size_t mask_bytes  = (size_t)WORDS * NB * sizeof(ull);

    if (ws_size >= out_t_bytes + mask_bytes) {
        float* out_t = (float*)d_ws;
        ull*   mask  = (ull*)((char*)d_ws + out_t_bytes);

        hipMemsetAsync(out_t, 0, out_t_bytes, stream);
        pack_spikes<<<dim3(WORDS * 64 / 256, NB), 256, 0, stream>>>(rec_z, mask);
        syn_scatter_t<<<blocks, 256, 0, stream>>>(
            (const int4*)synidx, (const float4*)weights, (const int4*)synids,
            mask, out_t, n_post, n_syn);
        combine_basis<<<(rows + 255) / 256, 256, 0, stream>>>(out_t, basis, out, rows);
    } else {
        // Fallback: direct 5-atomic scatter.
        ull* mask = (ull*)d_ws;
        hipMemsetAsync(d_out, 0, (size_t)out_size * sizeof(float), stream);
        pack_spikes<<<dim3(WORDS * 64 / 256, NB), 256, 0, stream>>>(rec_z, mask);
        syn_scatter_direct<<<blocks, 256, 0, stream>>>(
            (const int4*)synidx, (const float4*)weights, (const int4*)synids,
            basis, mask, out, n_post, n_syn);
    }
}